// Round 9
// baseline (21.643 us; speedup 1.0000x reference)
//
#include <hip/hip_runtime.h>

// Problem constants: B=2048, D=2048, H=16, Q=128, N=8192, V=128
// Identity: softmax rows sum to 1 => attn_rowsum == 1, so
//   out[b,:] = x[b,:] + c,  c[d] = sum_k vmean[k & 127] * Wo[d, k],
//   vmean = mean_n values[n,:].
// 3 dispatches (no grid-wide sync in any form; R4/R6 lessons):
//   D1 (128 blks):  values colsum -> partial[128][128]           [4 MB HBM]
//   D2 (1024 blks): Wo 2 rows/block preloaded to regs (overlaps the 64 KB
//                   L2-resident vmean prologue), c per block      [16 MB HBM]
//   D3 (1024 blks): out = x + c, 2 rows/block, nontemporal        [32 MB HBM]
// NOTE: __builtin_nontemporal_* requires native vector types, not
// HIP_vector_type (float4) — use ext_vector_type(4) pointers.

#define NROWS 8192
#define VDIM  128
#define DDIM  2048
#define BDIM  2048
#define PB    128     // D1 blocks / partial rows

typedef float nf4 __attribute__((ext_vector_type(4)));

__device__ __forceinline__ float4 nt_load4(const float4* p) {
    nf4 v = __builtin_nontemporal_load((const nf4*)p);
    return make_float4(v.x, v.y, v.z, v.w);
}
__device__ __forceinline__ void nt_store4(float4 v, float4* p) {
    nf4 n = {v.x, v.y, v.z, v.w};
    __builtin_nontemporal_store(n, (nf4*)p);
}

// ---------------------------------------------------------------------------
// D1: values colsum partials. 128 blocks x 256 threads; block sums 64 rows
// (2048 f4); thread sums 8 f4 at stride 256 (col-quad t&31 invariant).
__global__ void __launch_bounds__(256) colsum_kernel(
    const float4* __restrict__ vals4,
    float4* __restrict__ partial4)   // [128][32] f4
{
    __shared__ float4 s[256];
    const int t = threadIdx.x;
    const int bid = blockIdx.x;
    float4 acc = make_float4(0.f, 0.f, 0.f, 0.f);
    const int base = bid * 2048;
#pragma unroll
    for (int j = 0; j < 8; ++j) {
        float4 v = vals4[base + t + 256 * j];
        acc.x += v.x; acc.y += v.y; acc.z += v.z; acc.w += v.w;
    }
    s[t] = acc;
    __syncthreads();
    if (t < 32) {
        float4 r = s[t];
#pragma unroll
        for (int k = 1; k < 8; ++k) {
            float4 v = s[t + 32 * k];
            r.x += v.x; r.y += v.y; r.z += v.z; r.w += v.w;
        }
        partial4[bid * 32 + t] = r;
    }
}

// ---------------------------------------------------------------------------
// D2: c[d] for d = bid*2, bid*2+1, directly from Wo (full-chip width).
// Wo rows preloaded to registers FIRST (16 KB/block) so the HBM read
// overlaps the L2-resident vmean reduce. Both f4s a thread holds share
// vmean quad (t&31): dot = (w0+w1).vm.
__global__ void __launch_bounds__(256) c_kernel(
    const float4* __restrict__ partial4,  // [128][32] f4 (64 KB, L2)
    const float4* __restrict__ Wo4,
    float2* __restrict__ cvec2)           // [1024] f2 = c[2048]
{
    __shared__ float4 s[256];
    __shared__ float2 s2[256];
    __shared__ float4 vm_lds[32];
    const int t = threadIdx.x;
    const int d0 = blockIdx.x * 2;

    // issue Wo loads first (16 KB -> registers, nontemporal: read-once)
    float4 w[2][2];
#pragma unroll
    for (int r = 0; r < 2; ++r) {
        const float4* row = Wo4 + (size_t)(d0 + r) * 512;
        w[r][0] = nt_load4(&row[t]);
        w[r][1] = nt_load4(&row[t + 256]);
    }

    // vmean: partial 128x32 f4 = 4096 f4; 16 per thread; quad (t&31) invariant
    float4 acc = make_float4(0.f, 0.f, 0.f, 0.f);
#pragma unroll
    for (int j = 0; j < 16; ++j) {
        float4 v = partial4[t + 256 * j];
        acc.x += v.x; acc.y += v.y; acc.z += v.z; acc.w += v.w;
    }
    s[t] = acc;
    __syncthreads();
    if (t < 32) {
        float4 r = s[t];
#pragma unroll
        for (int k = 1; k < 8; ++k) {
            float4 v = s[t + 32 * k];
            r.x += v.x; r.y += v.y; r.z += v.z; r.w += v.w;
        }
        const float inv = 1.0f / (float)NROWS;
        r.x *= inv; r.y *= inv; r.z *= inv; r.w *= inv;
        vm_lds[t] = r;
    }
    __syncthreads();

    // per-thread dots for the 2 rows
    const float4 vm = vm_lds[t & 31];
    float2 dots;
#pragma unroll
    for (int r = 0; r < 2; ++r) {
        float4 a = w[r][0], b = w[r][1];
        a.x += b.x; a.y += b.y; a.z += b.z; a.w += b.w;
        float dv = a.x * vm.x + a.y * vm.y + a.z * vm.z + a.w * vm.w;
        if (r == 0) dots.x = dv; else dots.y = dv;
    }
    s2[t] = dots;
    __syncthreads();

    // reduce 256 partial dot-pairs -> c[d0], c[d0+1]
    if (t < 64) {
        float2 r = s2[t];
#pragma unroll
        for (int k = 1; k < 4; ++k) {
            float2 v = s2[t + 64 * k];
            r.x += v.x; r.y += v.y;
        }
#pragma unroll
        for (int off = 32; off; off >>= 1) {
            r.x += __shfl_down(r.x, off);
            r.y += __shfl_down(r.y, off);
        }
        if (t == 0) cvec2[blockIdx.x] = r;
    }
}

// ---------------------------------------------------------------------------
// D3: out[b,d] = x[b,d] + c[d]. 1024 blocks, 2 rows each, nontemporal
// (x read once, out written once — skip L2 allocate).
__global__ void __launch_bounds__(256) add_kernel(
    const float4* __restrict__ x4,
    const float* __restrict__ cvec,
    float4* __restrict__ out4)
{
    const float4* __restrict__ c4 = (const float4*)cvec;
    const int t = threadIdx.x;
    const size_t base = (size_t)blockIdx.x * 1024 + t;  // 2 rows = 1024 f4
    float4 xv0 = nt_load4(&x4[base]);
    float4 xv1 = nt_load4(&x4[base + 256]);
    float4 xv2 = nt_load4(&x4[base + 512]);
    float4 xv3 = nt_load4(&x4[base + 768]);
    float4 cv0 = c4[t];
    float4 cv1 = c4[t + 256];
    xv0.x += cv0.x; xv0.y += cv0.y; xv0.z += cv0.z; xv0.w += cv0.w;
    xv1.x += cv1.x; xv1.y += cv1.y; xv1.z += cv1.z; xv1.w += cv1.w;
    xv2.x += cv0.x; xv2.y += cv0.y; xv2.z += cv0.z; xv2.w += cv0.w;
    xv3.x += cv1.x; xv3.y += cv1.y; xv3.z += cv1.z; xv3.w += cv1.w;
    nt_store4(xv0, &out4[base]);
    nt_store4(xv1, &out4[base + 256]);
    nt_store4(xv2, &out4[base + 512]);
    nt_store4(xv3, &out4[base + 768]);
}

// ---------------------------------------------------------------------------
extern "C" void kernel_launch(void* const* d_in, const int* in_sizes, int n_in,
                              void* d_out, int out_size, void* d_ws, size_t ws_size,
                              hipStream_t stream) {
    // inputs: 0=x [B,D], 1=keys (unused), 2=values [N,V], 3=Wq (unused), 4=Wo [D,H*V]
    const float4* vals4 = (const float4*)d_in[2];
    const float4* Wo4   = (const float4*)d_in[4];
    const float4* x4    = (const float4*)d_in[0];
    float4* out4 = (float4*)d_out;
    char* ws = (char*)d_ws;

    float4* partial4 = (float4*)ws;               // 128*32 f4 = 64 KB
    float2* cvec2    = (float2*)(ws + 65536);     // 1024 f2 = 8 KB

    colsum_kernel<<<PB, 256, 0, stream>>>(vals4, partial4);
    c_kernel<<<1024, 256, 0, stream>>>(partial4, Wo4, cvec2);
    add_kernel<<<1024, 256, 0, stream>>>(x4, (const float*)cvec2, out4);
}

// Round 10
// 20.610 us; speedup vs baseline: 1.0501x; 1.0501x over previous
//
#include <hip/hip_runtime.h>

// Problem constants: B=2048, D=2048, H=16, Q=128, N=8192, V=128
// Identity: softmax rows sum to 1 => attn_rowsum == 1, so
//   out[b,:] = x[b,:] + c,  c[d] = sum_k vmean[k & 127] * Wo[d, k],
//   vmean = mean_n values[n,:].
// 3 dispatches (no grid-wide sync: R4 grid.sync ~170us, R6 manual barrier
// diverges under graph replay; no nontemporal: R9 showed inputs are
// L3-resident across replays and nt bypass regressed 1.6us):
//   D1 (128 blks):  values colsum -> partial[128][128]           [4 MB]
//   D2 (512 blks):  Wo 4 rows/block preloaded to regs (overlaps the 64 KB
//                   L2-resident vmean prologue), c per block      [16 MB]
//   D3 (2048 blks): out = x + c, one row per block                [32 MB]

#define NROWS 8192
#define VDIM  128
#define DDIM  2048
#define BDIM  2048
#define PB    128     // D1 blocks / partial rows

// ---------------------------------------------------------------------------
// D1: values colsum partials. 128 blocks x 256 threads; block sums 64 rows
// (2048 f4); thread sums 8 f4 at stride 256 (col-quad t&31 invariant).
__global__ void __launch_bounds__(256) colsum_kernel(
    const float4* __restrict__ vals4,
    float4* __restrict__ partial4)   // [128][32] f4
{
    __shared__ float4 s[256];
    const int t = threadIdx.x;
    const int bid = blockIdx.x;
    float4 acc = make_float4(0.f, 0.f, 0.f, 0.f);
    const int base = bid * 2048;
#pragma unroll
    for (int j = 0; j < 8; ++j) {
        float4 v = vals4[base + t + 256 * j];
        acc.x += v.x; acc.y += v.y; acc.z += v.z; acc.w += v.w;
    }
    s[t] = acc;
    __syncthreads();
    if (t < 32) {
        float4 r = s[t];
#pragma unroll
        for (int k = 1; k < 8; ++k) {
            float4 v = s[t + 32 * k];
            r.x += v.x; r.y += v.y; r.z += v.z; r.w += v.w;
        }
        partial4[bid * 32 + t] = r;
    }
}

// ---------------------------------------------------------------------------
// D2: c[d] for d = bid*4 .. +4, directly from Wo.
// Preload 4 Wo rows (2 f4/thread/row) into registers FIRST so the HBM/L3
// read overlaps the L2-resident vmean reduce. Both f4s of a row share the
// same vmean quad (t&31), so dot = (w0+w1).vm.
__global__ void __launch_bounds__(256) c_kernel(
    const float4* __restrict__ partial4,  // [128][32] f4 (64 KB, L2)
    const float4* __restrict__ Wo4,
    float4* __restrict__ cvec4)           // [512] f4 = c[2048]
{
    __shared__ float4 s[256];
    __shared__ float4 vm_lds[32];
    const int t = threadIdx.x;
    const int d0 = blockIdx.x * 4;

    // issue Wo loads first (32 KB -> registers)
    float4 w[4][2];
#pragma unroll
    for (int r = 0; r < 4; ++r) {
        const float4* row = Wo4 + (size_t)(d0 + r) * 512;
        w[r][0] = row[t];
        w[r][1] = row[t + 256];
    }

    // vmean: partial 128x32 f4 = 4096 f4; 16 per thread; quad (t&31) invariant
    float4 acc = make_float4(0.f, 0.f, 0.f, 0.f);
#pragma unroll
    for (int j = 0; j < 16; ++j) {
        float4 v = partial4[t + 256 * j];
        acc.x += v.x; acc.y += v.y; acc.z += v.z; acc.w += v.w;
    }
    s[t] = acc;
    __syncthreads();
    if (t < 32) {
        float4 r = s[t];
#pragma unroll
        for (int k = 1; k < 8; ++k) {
            float4 v = s[t + 32 * k];
            r.x += v.x; r.y += v.y; r.z += v.z; r.w += v.w;
        }
        const float inv = 1.0f / (float)NROWS;
        r.x *= inv; r.y *= inv; r.z *= inv; r.w *= inv;
        vm_lds[t] = r;
    }
    __syncthreads();

    // per-thread dots for the 4 rows
    const float4 vm = vm_lds[t & 31];
    float4 dots;
    {
        float* dp = (float*)&dots;
#pragma unroll
        for (int r = 0; r < 4; ++r) {
            float4 a = w[r][0], b = w[r][1];
            a.x += b.x; a.y += b.y; a.z += b.z; a.w += b.w;
            dp[r] = a.x * vm.x + a.y * vm.y + a.z * vm.z + a.w * vm.w;
        }
    }
    s[t] = dots;
    __syncthreads();

    // reduce 256 partial dot-quads -> 1 float4 (4 c values)
    if (t < 64) {
        float4 r = s[t];
#pragma unroll
        for (int k = 1; k < 4; ++k) {
            float4 v = s[t + 64 * k];
            r.x += v.x; r.y += v.y; r.z += v.z; r.w += v.w;
        }
#pragma unroll
        for (int off = 32; off; off >>= 1) {
            r.x += __shfl_down(r.x, off);
            r.y += __shfl_down(r.y, off);
            r.z += __shfl_down(r.z, off);
            r.w += __shfl_down(r.w, off);
        }
        if (t == 0) cvec4[blockIdx.x] = r;
    }
}

// ---------------------------------------------------------------------------
// D3: out[b,d] = x[b,d] + c[d]. 2048 blocks, one row each (proven R5/R7).
__global__ void __launch_bounds__(256) add_kernel(
    const float4* __restrict__ x4,
    const float* __restrict__ cvec,
    float4* __restrict__ out4)
{
    const float4* __restrict__ c4 = (const float4*)cvec;
    const int t = threadIdx.x;
    const size_t base = (size_t)blockIdx.x * 512 + t;
    float4 xv0 = x4[base];
    float4 xv1 = x4[base + 256];
    float4 cv0 = c4[t];
    float4 cv1 = c4[t + 256];
    xv0.x += cv0.x; xv0.y += cv0.y; xv0.z += cv0.z; xv0.w += cv0.w;
    xv1.x += cv1.x; xv1.y += cv1.y; xv1.z += cv1.z; xv1.w += cv1.w;
    out4[base] = xv0;
    out4[base + 256] = xv1;
}

// ---------------------------------------------------------------------------
extern "C" void kernel_launch(void* const* d_in, const int* in_sizes, int n_in,
                              void* d_out, int out_size, void* d_ws, size_t ws_size,
                              hipStream_t stream) {
    // inputs: 0=x [B,D], 1=keys (unused), 2=values [N,V], 3=Wq (unused), 4=Wo [D,H*V]
    const float4* vals4 = (const float4*)d_in[2];
    const float4* Wo4   = (const float4*)d_in[4];
    const float4* x4    = (const float4*)d_in[0];
    float4* out4 = (float4*)d_out;
    char* ws = (char*)d_ws;

    float4* partial4 = (float4*)ws;               // 128*32 f4 = 64 KB
    float4* cvec4    = (float4*)(ws + 65536);     // 512 f4 = 8 KB

    colsum_kernel<<<PB, 256, 0, stream>>>(vals4, partial4);
    c_kernel<<<512, 256, 0, stream>>>(partial4, Wo4, cvec4);
    add_kernel<<<2048, 256, 0, stream>>>(x4, (const float*)cvec4, out4);
}

// Round 11
// 19.815 us; speedup vs baseline: 1.0923x; 1.0401x over previous
//
#include <hip/hip_runtime.h>

// Problem constants: B=2048, D=2048, H=16, Q=128, N=8192, V=128
// Identity: softmax rows sum to 1 => attn_rowsum == 1, so
//   out[b,:] = x[b,:] + c,  c[d] = sum_k vmean[k & 127] * Wo[d, k],
//   vmean = mean_n values[n,:].
// FINAL (= R7 best-measured, 20.02 us): 3 dispatches, no grid-wide sync
// (R4: grid.sync ~170us/sync on 8-XCD; R6: manual atomic barrier diverges
// under graph replay), no nontemporal (R9: inputs L3-resident, nt regressed).
//   D1 (64 blks):   values colsum -> partial[64][128]            [4 MB]
//   D2 (512 blks):  Wo 4 rows/block preloaded to regs (overlaps the 32 KB
//                   L2-resident vmean prologue), c per block      [16 MB]
//   D3 (2048 blks): out = x + c, one row per block                [32 MB]
// Session floor: ~20 us = ~4.6 us fixed graph/event overhead + ~1-2 us
// dispatch gaps + ~14 us device work (52 MB mandatory traffic, L3-warm).

#define NROWS 8192
#define VDIM  128
#define DDIM  2048
#define BDIM  2048

// ---------------------------------------------------------------------------
// D1: values colsum partials. 64 blocks x 256 threads; block reads 128 rows
// (4096 f4), thread sums 16 f4 at stride 256 (col-quad t&31 invariant).
__global__ void __launch_bounds__(256) colsum_kernel(
    const float4* __restrict__ vals4,
    float4* __restrict__ partial4)   // [64][32] f4
{
    __shared__ float4 s[256];
    const int t = threadIdx.x;
    const int bid = blockIdx.x;
    float4 acc = make_float4(0.f, 0.f, 0.f, 0.f);
    const int base = bid * 4096;
#pragma unroll
    for (int j = 0; j < 16; ++j) {
        float4 v = vals4[base + t + 256 * j];
        acc.x += v.x; acc.y += v.y; acc.z += v.z; acc.w += v.w;
    }
    s[t] = acc;
    __syncthreads();
    if (t < 32) {
        float4 r = s[t];
#pragma unroll
        for (int k = 1; k < 8; ++k) {
            float4 v = s[t + 32 * k];
            r.x += v.x; r.y += v.y; r.z += v.z; r.w += v.w;
        }
        partial4[bid * 32 + t] = r;
    }
}

// ---------------------------------------------------------------------------
// D2: c[d] for d = bid*4 .. +4, directly from Wo.
// Preload 4 Wo rows (2 f4/thread/row) into registers FIRST so the 32 KB
// HBM/L3 read overlaps the L2-resident vmean reduce. Both f4s of a row
// share the same vmean quad (t&31), so dot = (w0+w1).vm.
__global__ void __launch_bounds__(256) c_kernel(
    const float4* __restrict__ partial4,  // [64][32] f4 (32 KB, L2)
    const float4* __restrict__ Wo4,
    float4* __restrict__ cvec4)           // [512] f4 = c[2048]
{
    __shared__ float4 s[256];
    __shared__ float4 vm_lds[32];
    const int t = threadIdx.x;
    const int d0 = blockIdx.x * 4;

    // issue Wo loads first (32 KB -> registers)
    float4 w[4][2];
#pragma unroll
    for (int r = 0; r < 4; ++r) {
        const float4* row = Wo4 + (size_t)(d0 + r) * 512;
        w[r][0] = row[t];
        w[r][1] = row[t + 256];
    }

    // vmean: partial 64x32 f4 = 2048 f4; 8 per thread; quad (t&31) invariant
    float4 acc = make_float4(0.f, 0.f, 0.f, 0.f);
#pragma unroll
    for (int j = 0; j < 8; ++j) {
        float4 v = partial4[t + 256 * j];
        acc.x += v.x; acc.y += v.y; acc.z += v.z; acc.w += v.w;
    }
    s[t] = acc;
    __syncthreads();
    if (t < 32) {
        float4 r = s[t];
#pragma unroll
        for (int k = 1; k < 8; ++k) {
            float4 v = s[t + 32 * k];
            r.x += v.x; r.y += v.y; r.z += v.z; r.w += v.w;
        }
        const float inv = 1.0f / (float)NROWS;
        r.x *= inv; r.y *= inv; r.z *= inv; r.w *= inv;
        vm_lds[t] = r;
    }
    __syncthreads();

    // per-thread dots for the 4 rows
    const float4 vm = vm_lds[t & 31];
    float4 dots;
    {
        float* dp = (float*)&dots;
#pragma unroll
        for (int r = 0; r < 4; ++r) {
            float4 a = w[r][0], b = w[r][1];
            a.x += b.x; a.y += b.y; a.z += b.z; a.w += b.w;
            dp[r] = a.x * vm.x + a.y * vm.y + a.z * vm.z + a.w * vm.w;
        }
    }
    s[t] = dots;
    __syncthreads();

    // reduce 256 partial dot-quads -> 1 float4 (4 c values)
    if (t < 64) {
        float4 r = s[t];
#pragma unroll
        for (int k = 1; k < 4; ++k) {
            float4 v = s[t + 64 * k];
            r.x += v.x; r.y += v.y; r.z += v.z; r.w += v.w;
        }
#pragma unroll
        for (int off = 32; off; off >>= 1) {
            r.x += __shfl_down(r.x, off);
            r.y += __shfl_down(r.y, off);
            r.z += __shfl_down(r.z, off);
            r.w += __shfl_down(r.w, off);
        }
        if (t == 0) cvec4[blockIdx.x] = r;
    }
}

// ---------------------------------------------------------------------------
// D3: out[b,d] = x[b,d] + c[d]. 2048 blocks, one row each.
__global__ void __launch_bounds__(256) add_kernel(
    const float4* __restrict__ x4,
    const float* __restrict__ cvec,
    float4* __restrict__ out4)
{
    const float4* __restrict__ c4 = (const float4*)cvec;
    const int t = threadIdx.x;
    const size_t base = (size_t)blockIdx.x * 512 + t;
    float4 xv0 = x4[base];
    float4 xv1 = x4[base + 256];
    float4 cv0 = c4[t];
    float4 cv1 = c4[t + 256];
    xv0.x += cv0.x; xv0.y += cv0.y; xv0.z += cv0.z; xv0.w += cv0.w;
    xv1.x += cv1.x; xv1.y += cv1.y; xv1.z += cv1.z; xv1.w += cv1.w;
    out4[base] = xv0;
    out4[base + 256] = xv1;
}

// ---------------------------------------------------------------------------
extern "C" void kernel_launch(void* const* d_in, const int* in_sizes, int n_in,
                              void* d_out, int out_size, void* d_ws, size_t ws_size,
                              hipStream_t stream) {
    // inputs: 0=x [B,D], 1=keys (unused), 2=values [N,V], 3=Wq (unused), 4=Wo [D,H*V]
    const float4* vals4 = (const float4*)d_in[2];
    const float4* Wo4   = (const float4*)d_in[4];
    const float4* x4    = (const float4*)d_in[0];
    float4* out4 = (float4*)d_out;
    char* ws = (char*)d_ws;

    float4* partial4 = (float4*)ws;               // 64*32 f4 = 32 KB
    float4* cvec4    = (float4*)(ws + 32768);     // 512 f4 = 8 KB

    colsum_kernel<<<64, 256, 0, stream>>>(vals4, partial4);
    c_kernel<<<512, 256, 0, stream>>>(partial4, Wo4, cvec4);
    add_kernel<<<2048, 256, 0, stream>>>(x4, (const float*)cvec4, out4);
}